// Round 11
// baseline (565.283 us; speedup 1.0000x reference)
//
#include <hip/hip_runtime.h>
#include <stdint.h>

#define DIN   64
#define HDIM  64
#define EIN   16
#define EHID  128     // edge hidden width
#define HH    4096    // HDIM*HDIM
#define TC    8256    // T cols: 8192 main + 64 bias
#define STEPS 3

typedef short bf16x8 __attribute__((ext_vector_type(8)));
typedef float f32x4  __attribute__((ext_vector_type(4)));

// storage col perm (msg/agg/x layout): mem col l holds semantic o = (l&3)*16 + (l>>2)
// inverse: semantic o stored at p = (o&15)*4 + (o>>4)

__device__ __forceinline__ unsigned short f32_to_bf16(float f) {
    union { float f; uint32_t u; } v; v.f = f;
    uint32_t r = v.u + 0x7fffu + ((v.u >> 16) & 1u);   // RNE
    return (unsigned short)(r >> 16);
}
__device__ __forceinline__ float bfu_to_f(unsigned short u) {
    union { uint32_t u; float f; } v; v.u = (uint32_t)u << 16; return v.f;
}

// ---- merged prologue: [0,nbN) node_mlp | [nbN,+nbE) edge_mlp(MFMA) | [+nbB) bmat+cbp | rest hist ----
__global__ void k_pro(const float* __restrict__ nf, const float* __restrict__ W0,
                      const float* __restrict__ b0, unsigned short* __restrict__ outbf,
                      const float* __restrict__ ef, const float* __restrict__ We1,
                      const float* __restrict__ be1, unsigned short* __restrict__ h,
                      const float* __restrict__ We2, const float* __restrict__ be2,
                      unsigned short* __restrict__ BmatT,
                      const float* __restrict__ cbias, float* __restrict__ cbp,
                      const int* __restrict__ src, const int* __restrict__ dst,
                      int* __restrict__ cntS, int* __restrict__ cntD,
                      int n_nodes, int n_edges, int nbN, int nbE, int nbB) {
    __shared__ float smem[DIN * HDIM];   // 16 KB (node path only)
    int b = blockIdx.x, tid = threadIdx.x;
    if (b < nbN) {
        // node MLP: v[n,o] = relu(n_feat[n,:]@W0[:,o]+b0[o]); stored PERMUTED bf16
        for (int i = tid; i < DIN * HDIM; i += 256) smem[i] = W0[i];
        __syncthreads();
        int node = b * 4 + (tid >> 6);
        int o = tid & 63;
        if (node >= n_nodes) return;
        float xr = nf[node * DIN + o];
        float acc = b0[o];
#pragma unroll 8
        for (int i = 0; i < DIN; ++i)
            acc += __shfl(xr, i, 64) * smem[i * HDIM + o];
        float v = fmaxf(acc, 0.f);
        int p = ((o & 15) << 2) | (o >> 4);          // inverse storage perm
        outbf[node * HDIM + p] = f32_to_bf16(v);
    } else if (b < nbN + nbE) {
        // edge MLP via MFMA: 64 edges/block (16/wave), K=16 zero-padded to 32.
        // h stored with per-64-group col perm sigma (inverse baked into BmatT k-index).
        int wave = tid >> 6, lane = tid & 63;
        int r = lane & 15, q = lane >> 4;
        int e0 = (b - nbN) * 64 + wave * 16;
        if (e0 >= n_edges) return;           // wave-uniform
        bf16x8 afr = (bf16x8){};
        bf16x8 bfr[8];
#pragma unroll
        for (int nt = 0; nt < 8; ++nt) bfr[nt] = (bf16x8){};
        if (q < 2) {
            int ea = e0 + r; if (ea >= n_edges) ea = n_edges - 1;
            const float* xa = ef + (size_t)ea * EIN + q * 8;
#pragma unroll
            for (int j = 0; j < 8; ++j) afr[j] = (short)f32_to_bf16(xa[j]);
#pragma unroll
            for (int nt = 0; nt < 8; ++nt)
#pragma unroll
                for (int j = 0; j < 8; ++j)
                    bfr[nt][j] = (short)f32_to_bf16(We1[(q * 8 + j) * EHID + nt * 16 + r]);
        }
        f32x4 acc[8];
#pragma unroll
        for (int nt = 0; nt < 8; ++nt)
            acc[nt] = __builtin_amdgcn_mfma_f32_16x16x32_bf16(afr, bfr[nt], (f32x4){}, 0, 0, 0);
        float bias[8];
#pragma unroll
        for (int nt = 0; nt < 8; ++nt) bias[nt] = be1[nt * 16 + r];
#pragma unroll
        for (int rg = 0; rg < 4; ++rg) {
            int e = e0 + q * 4 + rg;         // C/D: col=lane&15, row=quad*4+reg
            if (e >= n_edges) continue;
            ushort4 pk0, pk1;
            pk0.x = f32_to_bf16(fmaxf(acc[0][rg] + bias[0], 0.f));
            pk0.y = f32_to_bf16(fmaxf(acc[1][rg] + bias[1], 0.f));
            pk0.z = f32_to_bf16(fmaxf(acc[2][rg] + bias[2], 0.f));
            pk0.w = f32_to_bf16(fmaxf(acc[3][rg] + bias[3], 0.f));
            pk1.x = f32_to_bf16(fmaxf(acc[4][rg] + bias[4], 0.f));
            pk1.y = f32_to_bf16(fmaxf(acc[5][rg] + bias[5], 0.f));
            pk1.z = f32_to_bf16(fmaxf(acc[6][rg] + bias[6], 0.f));
            pk1.w = f32_to_bf16(fmaxf(acc[7][rg] + bias[7], 0.f));
            *(ushort4*)(h + (size_t)e * EHID + 4 * r) = pk0;
            *(ushort4*)(h + (size_t)e * EHID + 64 + 4 * r) = pk1;
        }
    } else if (b < nbN + nbE + nbB) {
        // BmatT: epilogue-pack perm (128-group main / 64-group bias) + T'' layout
        // + h-perm sigma (k index) + x-storage perm (i index)
        int t = (b - nbN - nbE) * 256 + tid;
        if (b == nbN + nbE && tid < 64)
            cbp[tid] = cbias[(tid & 3) * 16 + (tid >> 2)];   // permuted conv_bias
        if (t >= TC * 64) return;
        int c = t >> 6, i = t & 63;
        int isem = (i & 3) * 16 + (i >> 2);        // x stored permuted
        int m;
        if (c < 8192) {
            int g = c & 127;                       // mfma col nt*16+r -> mem col 8r+nt
            m = (c & ~127) + 8 * (g & 15) + (g >> 4);
        } else {
            int g = c & 63;                        // bias block keeps 4r+nt
            m = (c & ~63) + 4 * (g & 15) + (g >> 4);
        }
        float v;
        if (m < 8192) {
            int p = ((m >> 11) << 5) | (m & 31);                     // stored h position
            int k = (p & 64) + ((p & 3) << 4) + ((p >> 2) & 15);     // true h channel
            int o = (m >> 5) & 63;
            v = We2[k * HH + isem * 64 + o];
        } else {
            v = be2[isem * 64 + (m - 8192)];
        }
        BmatT[t] = f32_to_bf16(v);
    } else {
        // histogram src and dst
        int e = (b - nbN - nbE - nbB) * 256 + tid;
        if (e >= n_edges) return;
        atomicAdd(&cntS[src[e]], 1);
        atomicAdd(&cntD[dst[e]], 1);
    }
}

// T[n, m] = sum_i x[n,i]*B[i,m], bf16 out in T'' layout.
// A source: step 0 = outbf (bf16, permuted); steps>0 = aggp (f32, permuted) with
// relu(x+cbp) applied inline (numerically identical to old k_agg+outbf path).
__global__ void k_T(const unsigned short* __restrict__ outbf, const float* __restrict__ aggp,
                    const float* __restrict__ cbp, const unsigned short* __restrict__ BmatT,
                    unsigned short* __restrict__ T, int n0, int n1) {
    int wave = threadIdx.x >> 6, lane = threadIdx.x & 63;
    int r = lane & 15, q = lane >> 4;
    int eb = n0 + blockIdx.y * 128;
    float cb[16];
    if (aggp) {
#pragma unroll
        for (int j = 0; j < 8; ++j) { cb[j] = cbp[q * 8 + j]; cb[8 + j] = cbp[32 + q * 8 + j]; }
    }
    if (blockIdx.x < 16) {
        int cbase = blockIdx.x * 512 + wave * 128;
        bf16x8 bfr[8][2];
#pragma unroll
        for (int nt = 0; nt < 8; ++nt) {
            size_t cofs = (size_t)(cbase + nt * 16 + r) * 64;
            bfr[nt][0] = *(const bf16x8*)(BmatT + cofs + q * 8);
            bfr[nt][1] = *(const bf16x8*)(BmatT + cofs + 32 + q * 8);
        }
#pragma unroll
        for (int mt = 0; mt < 8; ++mt) {
            int e = eb + mt * 16 + r;
            if (e >= n1) e = n1 - 1;
            bf16x8 afr0, afr1;
            if (aggp) {
                const float* ap = aggp + (size_t)e * 64 + q * 8;
#pragma unroll
                for (int j = 0; j < 8; ++j) {
                    afr0[j] = (short)f32_to_bf16(fmaxf(ap[j] + cb[j], 0.f));
                    afr1[j] = (short)f32_to_bf16(fmaxf(ap[32 + j] + cb[8 + j], 0.f));
                }
            } else {
                afr0 = *(const bf16x8*)(outbf + (size_t)e * 64 + q * 8);
                afr1 = *(const bf16x8*)(outbf + (size_t)e * 64 + 32 + q * 8);
            }
            f32x4 acc[8];
#pragma unroll
            for (int nt = 0; nt < 8; ++nt) {
                acc[nt] = __builtin_amdgcn_mfma_f32_16x16x32_bf16(afr0, bfr[nt][0], (f32x4){}, 0, 0, 0);
                acc[nt] = __builtin_amdgcn_mfma_f32_16x16x32_bf16(afr1, bfr[nt][1], acc[nt], 0, 0, 0);
            }
#pragma unroll
            for (int rg = 0; rg < 4; ++rg) {
                int n = eb + mt * 16 + q * 4 + rg;   // C/D: col=lane&15, row=quad*4+reg
                if (n >= n1) continue;
                ushort4 pa, pb;
                pa.x = f32_to_bf16(acc[0][rg]); pa.y = f32_to_bf16(acc[1][rg]);
                pa.z = f32_to_bf16(acc[2][rg]); pa.w = f32_to_bf16(acc[3][rg]);
                pb.x = f32_to_bf16(acc[4][rg]); pb.y = f32_to_bf16(acc[5][rg]);
                pb.z = f32_to_bf16(acc[6][rg]); pb.w = f32_to_bf16(acc[7][rg]);
                uint4 pk = { ((uint32_t)pa.y << 16) | pa.x, ((uint32_t)pa.w << 16) | pa.z,
                             ((uint32_t)pb.y << 16) | pb.x, ((uint32_t)pb.w << 16) | pb.z };
                *(uint4*)(T + (size_t)(n - n0) * TC + cbase + 8 * r) = pk;
            }
        }
    } else {
        if (wave != 0) return;               // bias tail: 64 cols only
        int cbase = 8192;
        bf16x8 bfr[4][2];
#pragma unroll
        for (int nt = 0; nt < 4; ++nt) {
            size_t cofs = (size_t)(cbase + nt * 16 + r) * 64;
            bfr[nt][0] = *(const bf16x8*)(BmatT + cofs + q * 8);
            bfr[nt][1] = *(const bf16x8*)(BmatT + cofs + 32 + q * 8);
        }
#pragma unroll
        for (int mt = 0; mt < 8; ++mt) {
            int e = eb + mt * 16 + r;
            if (e >= n1) e = n1 - 1;
            bf16x8 afr0, afr1;
            if (aggp) {
                const float* ap = aggp + (size_t)e * 64 + q * 8;
#pragma unroll
                for (int j = 0; j < 8; ++j) {
                    afr0[j] = (short)f32_to_bf16(fmaxf(ap[j] + cb[j], 0.f));
                    afr1[j] = (short)f32_to_bf16(fmaxf(ap[32 + j] + cb[8 + j], 0.f));
                }
            } else {
                afr0 = *(const bf16x8*)(outbf + (size_t)e * 64 + q * 8);
                afr1 = *(const bf16x8*)(outbf + (size_t)e * 64 + 32 + q * 8);
            }
            f32x4 acc[4];
#pragma unroll
            for (int nt = 0; nt < 4; ++nt) {
                acc[nt] = __builtin_amdgcn_mfma_f32_16x16x32_bf16(afr0, bfr[nt][0], (f32x4){}, 0, 0, 0);
                acc[nt] = __builtin_amdgcn_mfma_f32_16x16x32_bf16(afr1, bfr[nt][1], acc[nt], 0, 0, 0);
            }
#pragma unroll
            for (int rg = 0; rg < 4; ++rg) {
                int n = eb + mt * 16 + q * 4 + rg;
                if (n >= n1) continue;
                ushort4 pk;
                pk.x = f32_to_bf16(acc[0][rg]);
                pk.y = f32_to_bf16(acc[1][rg]);
                pk.z = f32_to_bf16(acc[2][rg]);
                pk.w = f32_to_bf16(acc[3][rg]);
                *(ushort4*)(T + (size_t)(n - n0) * TC + cbase + 4 * r) = pk;
            }
        }
    }
}

// per src-node wave, MFMA: msg for 16 edges x 64 o = h @ T''[n];
// epilogue scatters directly: atomicAdd into agg[dst[e]] (permuted cols 4r..4r+3)
__global__ void k_msg(const unsigned short* __restrict__ h, const unsigned short* __restrict__ T,
                      const int* __restrict__ offS, const int* __restrict__ permS,
                      const int* __restrict__ dst, float* __restrict__ agg, int n0, int n1) {
    int wave = threadIdx.x >> 6, lane = threadIdx.x & 63;
    int n = n0 + blockIdx.x * 4 + wave;
    if (n >= n1) return;
    int beg = offS[n], end = offS[n + 1];
    if (beg == end) return;
    int r = lane & 15, q = lane >> 4;
    const unsigned short* Tb = T + (size_t)(n - n0) * TC;
    float bias[4];
#pragma unroll
    for (int nt = 0; nt < 4; ++nt)
        bias[nt] = bfu_to_f(Tb[8192 + nt * 16 + r]);
    for (int j0 = beg; j0 < end; j0 += 16) {
        int jc = j0 + r; if (jc >= end) jc = end - 1;
        int e = permS[jc];
        const unsigned short* he = h + (size_t)e * EHID;
        f32x4 acc[4] = {};
#pragma unroll
        for (int s = 0; s < 4; ++s) {        // K = 128 = 4*32
            bf16x8 afr = *(const bf16x8*)(he + s * 32 + q * 8);
#pragma unroll
            for (int nt = 0; nt < 4; ++nt) {
                bf16x8 bfr = *(const bf16x8*)(Tb + s * 2048 + (nt * 16 + r) * 32 + q * 8);
                acc[nt] = __builtin_amdgcn_mfma_f32_16x16x32_bf16(afr, bfr, acc[nt], 0, 0, 0);
            }
        }
#pragma unroll
        for (int rg = 0; rg < 4; ++rg) {
            int jr = j0 + q * 4 + rg;
            if (jr >= end) continue;
            int er = permS[jr];
            float* ag = agg + (size_t)dst[er] * 64 + 4 * r;
            atomicAdd(ag + 0, acc[0][rg] + bias[0]);
            atomicAdd(ag + 1, acc[1][rg] + bias[1]);
            atomicAdd(ag + 2, acc[2][rg] + bias[2]);
            atomicAdd(ag + 3, acc[3][rg] + bias[3]);
        }
    }
}

// exclusive prefix sum (one block per array; blockIdx.x: 0=S, 1=D)
__global__ void k_scan(const int* __restrict__ cntS, const int* __restrict__ cntD,
                       int* __restrict__ offS, int* __restrict__ offD,
                       int* __restrict__ curS, int* __restrict__ curD, int n, int total) {
    const int* cnt = blockIdx.x ? cntD : cntS;
    int* off = blockIdx.x ? offD : offS;
    int* cur = blockIdx.x ? curD : curS;
    __shared__ int part[256];
    int tid = threadIdx.x;
    int chunk = (n + 255) / 256;
    int c0 = tid * chunk, c1 = c0 + chunk; if (c1 > n) c1 = n; if (c0 > n) c0 = n;
    int s = 0;
    for (int i = c0; i < c1; ++i) s += cnt[i];
    part[tid] = s;
    __syncthreads();
    for (int st = 1; st < 256; st <<= 1) {
        int v = (tid >= st) ? part[tid - st] : 0;
        __syncthreads();
        part[tid] += v;
        __syncthreads();
    }
    int run = tid ? part[tid - 1] : 0;
    for (int i = c0; i < c1; ++i) { off[i] = run; cur[i] = run; run += cnt[i]; }
    if (tid == 0) off[n] = total;
}

__global__ void k_perm(const int* __restrict__ src,
                       int* __restrict__ curS, int* __restrict__ permS, int n_edges) {
    int e = blockIdx.x * 256 + threadIdx.x;
    if (e >= n_edges) return;
    permS[atomicAdd(&curS[src[e]], 1)] = e;
}

// grid MUST be 64 blocks (row stride 256 hardcoded); reads agg (permuted) + relu
__global__ void k_bn_stats(const float* __restrict__ agg, const float* __restrict__ cbp,
                           float* __restrict__ stat, int n_nodes) {
    __shared__ float s1[256], s2[256];
    int tid = threadIdx.x;
    int f = tid & 63, g = tid >> 6;
    float cb = cbp[f];
    float sum = 0.f, ss = 0.f;
    for (int r = blockIdx.x * 4 + g; r < n_nodes; r += 256) {
        float v = fmaxf(agg[r * HDIM + f] + cb, 0.f);
        sum += v; ss += v * v;
    }
    s1[tid] = sum; s2[tid] = ss;
    __syncthreads();
    if (tid < 64) {
        float A = s1[tid] + s1[64 + tid] + s1[128 + tid] + s1[192 + tid];
        float B = s2[tid] + s2[64 + tid] + s2[128 + tid] + s2[192 + tid];
        atomicAdd(&stat[tid], A);       // stat indexed by STORED col
        atomicAdd(&stat[64 + tid], B);
    }
}

// reads agg (permuted), recomputes v=relu(acc+cbias), BN, writes NATURAL layout
__global__ void k_bn_apply(const float* __restrict__ agg, const float* __restrict__ cbp,
                           const float* __restrict__ stat,
                           const float* __restrict__ gamma, const float* __restrict__ beta,
                           float* __restrict__ y, int n, int n_nodes) {
    int t = blockIdx.x * 256 + threadIdx.x;
    if (t >= n) return;
    int l = t & 63;
    int f = (l & 3) * 16 + (l >> 2);          // semantic feature of stored col l
    float v = fmaxf(agg[t] + cbp[l], 0.f);
    float mean = stat[l] / n_nodes;
    float var  = stat[64 + l] / n_nodes - mean * mean;   // population var
    float inv  = rsqrtf(var + 1e-5f);
    float scale = gamma[f] * inv;
    float shift = beta[f] - mean * scale;
    y[(t & ~63) | f] = v * scale + shift;
}

extern "C" void kernel_launch(void* const* d_in, const int* in_sizes, int n_in,
                              void* d_out, int out_size, void* d_ws, size_t ws_size,
                              hipStream_t stream) {
    const float* nf    = (const float*)d_in[0];
    const float* ef    = (const float*)d_in[1];
    const int*   src   = (const int*)d_in[2];
    const int*   dst   = (const int*)d_in[3];
    const float* W0    = (const float*)d_in[4];
    const float* b0    = (const float*)d_in[5];
    const float* We1   = (const float*)d_in[6];
    const float* be1   = (const float*)d_in[7];
    const float* We2   = (const float*)d_in[8];
    const float* be2   = (const float*)d_in[9];
    const float* cbias = (const float*)d_in[10];
    const float* gamma = (const float*)d_in[11];
    const float* beta  = (const float*)d_in[12];
    (void)n_in; (void)out_size;

    int n_nodes = in_sizes[0] / DIN;   // 10000
    int n_edges = in_sizes[2];         // 100000

    char* ws = (char*)d_ws;
    size_t off = 0;
    auto carve = [&](size_t bytes) -> void* {
        void* p = ws + off;
        off = (off + bytes + 255) & ~(size_t)255;
        return p;
    };
    unsigned short* h     = (unsigned short*)carve((size_t)n_edges * EHID * 2);  // 25.6 MB
    unsigned short* outbf = (unsigned short*)carve((size_t)n_nodes * HDIM * 2);
    unsigned short* BmatT = (unsigned short*)carve((size_t)TC * 64 * 2);
    int*            offS  = (int*)carve((size_t)(n_nodes + 1) * 4);
    int*            curS  = (int*)carve((size_t)n_nodes * 4);
    int*            permS = (int*)carve((size_t)n_edges * 4);
    float*          cbp   = (float*)carve(64 * 4);
    // zero region: stat(128f) + cntS(n) + cntD(n) + agg[0..2] (3 * n*64 f32)
    size_t zbytes = 128 * 4 + (size_t)2 * n_nodes * 4 + (size_t)3 * n_nodes * HDIM * 4;
    float* stat = (float*)carve(zbytes);
    int*   cntS = (int*)(stat + 128);
    int*   cntD = cntS + n_nodes;
    float* agg0 = (float*)(cntD + n_nodes);
    float* agg[3] = { agg0, agg0 + (size_t)n_nodes * HDIM, agg0 + (size_t)2 * n_nodes * HDIM };
    unsigned short* T = (unsigned short*)(ws + off);
    size_t avail = ws_size > off ? ws_size - off : 0;
    long tcap = (long)(avail / ((size_t)TC * 2));   // ws-capacity bound (node rows)
    if (tcap > n_nodes) tcap = n_nodes;
    if (tcap < 64) tcap = 64;
    long tchunk = tcap;   // fits whole graph with current ws (165 MB need, ~219 avail)

    hipMemsetAsync(stat, 0, zbytes, stream);

    int nbN = (n_nodes + 3) / 4;            // 2500
    int nbE = (n_edges + 63) / 64;          // 1563 (MFMA edge path: 64 edges/block)
    int nbB = (TC * 64 + 255) / 256;        // 2064
    int nbH = (n_edges + 255) / 256;        // 391
    k_pro<<<dim3(nbN + nbE + nbB + nbH), 256, 0, stream>>>(
        nf, W0, b0, outbf, ef, We1, be1, h, We2, be2, BmatT,
        cbias, cbp, src, dst, cntS, cntD, n_nodes, n_edges, nbN, nbE, nbB);
    // only src-grouping needed now (dst handled by atomics); reuse cntD slot as scratch
    k_scan<<<dim3(1), 256, 0, stream>>>(cntS, cntS, offS, offS, curS, curS, n_nodes, n_edges);
    k_perm<<<dim3((n_edges + 255) / 256), 256, 0, stream>>>(src, curS, permS, n_edges);

    for (int step = 0; step < STEPS; ++step) {
        const float* aggprev = (step == 0) ? nullptr : agg[step - 1];
        for (long n0 = 0; n0 < n_nodes; n0 += tchunk) {
            long n1 = n0 + tchunk; if (n1 > n_nodes) n1 = n_nodes;
            long cnt = n1 - n0;
            k_T<<<dim3(17, (cnt + 127) / 128), 256, 0, stream>>>(
                outbf, aggprev, cbp, BmatT, T, (int)n0, (int)n1);
            k_msg<<<dim3((cnt + 3) / 4), 256, 0, stream>>>(
                h, T, offS, permS, dst, agg[step], (int)n0, (int)n1);
        }
    }

    k_bn_stats<<<dim3(64), 256, 0, stream>>>(agg[2], cbp, stat, n_nodes);
    k_bn_apply<<<dim3((n_nodes * HDIM + 255) / 256), 256, 0, stream>>>(
        agg[2], cbp, stat, gamma, beta, (float*)d_out, n_nodes * HDIM, n_nodes);
}

// Round 12
// 466.122 us; speedup vs baseline: 1.2127x; 1.2127x over previous
//
#include <hip/hip_runtime.h>
#include <stdint.h>

#define DIN   64
#define HDIM  64
#define EIN   16
#define EHID  128     // edge hidden width
#define HH    4096    // HDIM*HDIM
#define TC    8256    // T cols: 8192 main + 64 bias
#define STEPS 3

typedef short bf16x8 __attribute__((ext_vector_type(8)));
typedef float f32x4  __attribute__((ext_vector_type(4)));

__device__ __forceinline__ unsigned short f32_to_bf16(float f) {
    union { float f; uint32_t u; } v; v.f = f;
    uint32_t r = v.u + 0x7fffu + ((v.u >> 16) & 1u);   // RNE
    return (unsigned short)(r >> 16);
}
__device__ __forceinline__ float bfu_to_f(unsigned short u) {
    union { uint32_t u; float f; } v; v.u = (uint32_t)u << 16; return v.f;
}

// ---- merged prologue: [0,nbN) node_mlp | [nbN,+nbE) edge_mlp(MFMA) | [+nbB) bmat | rest hist ----
__global__ void k_pro(const float* __restrict__ nf, const float* __restrict__ W0,
                      const float* __restrict__ b0, float* __restrict__ outb,
                      unsigned short* __restrict__ outbf,
                      const float* __restrict__ ef, const float* __restrict__ We1,
                      const float* __restrict__ be1, unsigned short* __restrict__ h,
                      const float* __restrict__ We2, const float* __restrict__ be2,
                      unsigned short* __restrict__ BmatT,
                      const int* __restrict__ src, const int* __restrict__ dst,
                      int* __restrict__ cntS, int* __restrict__ cntD,
                      int n_nodes, int n_edges, int nbN, int nbE, int nbB) {
    __shared__ float smem[DIN * HDIM];   // 16 KB (node path only)
    int b = blockIdx.x, tid = threadIdx.x;
    if (b < nbN) {
        // node MLP: out[n,o] = relu(n_feat[n,:]@W0[:,o]+b0[o]); 4 nodes/block
        for (int i = tid; i < DIN * HDIM; i += 256) smem[i] = W0[i];
        __syncthreads();
        int node = b * 4 + (tid >> 6);
        int o = tid & 63;
        if (node >= n_nodes) return;
        float xr = nf[node * DIN + o];
        float acc = b0[o];
#pragma unroll 8
        for (int i = 0; i < DIN; ++i)
            acc += __shfl(xr, i, 64) * smem[i * HDIM + o];
        float v = fmaxf(acc, 0.f);
        outb[node * HDIM + o] = v;
        outbf[node * HDIM + o] = f32_to_bf16(v);
    } else if (b < nbN + nbE) {
        // edge MLP via MFMA: 64 edges/block (16/wave), K=16 zero-padded to 32.
        // h stored with per-64-group col perm sigma (inverse baked into BmatT k-index).
        int wave = tid >> 6, lane = tid & 63;
        int r = lane & 15, q = lane >> 4;
        int e0 = (b - nbN) * 64 + wave * 16;
        if (e0 >= n_edges) return;           // wave-uniform
        bf16x8 afr = (bf16x8){};
        bf16x8 bfr[8];
#pragma unroll
        for (int nt = 0; nt < 8; ++nt) bfr[nt] = (bf16x8){};
        if (q < 2) {
            int ea = e0 + r; if (ea >= n_edges) ea = n_edges - 1;
            const float* xa = ef + (size_t)ea * EIN + q * 8;
#pragma unroll
            for (int j = 0; j < 8; ++j) afr[j] = (short)f32_to_bf16(xa[j]);
#pragma unroll
            for (int nt = 0; nt < 8; ++nt)
#pragma unroll
                for (int j = 0; j < 8; ++j)
                    bfr[nt][j] = (short)f32_to_bf16(We1[(q * 8 + j) * EHID + nt * 16 + r]);
        }
        f32x4 acc[8];
#pragma unroll
        for (int nt = 0; nt < 8; ++nt)
            acc[nt] = __builtin_amdgcn_mfma_f32_16x16x32_bf16(afr, bfr[nt], (f32x4){}, 0, 0, 0);
        float bias[8];
#pragma unroll
        for (int nt = 0; nt < 8; ++nt) bias[nt] = be1[nt * 16 + r];
#pragma unroll
        for (int rg = 0; rg < 4; ++rg) {
            int e = e0 + q * 4 + rg;         // C/D: col=lane&15, row=quad*4+reg
            if (e >= n_edges) continue;
            ushort4 pk0, pk1;
            pk0.x = f32_to_bf16(fmaxf(acc[0][rg] + bias[0], 0.f));
            pk0.y = f32_to_bf16(fmaxf(acc[1][rg] + bias[1], 0.f));
            pk0.z = f32_to_bf16(fmaxf(acc[2][rg] + bias[2], 0.f));
            pk0.w = f32_to_bf16(fmaxf(acc[3][rg] + bias[3], 0.f));
            pk1.x = f32_to_bf16(fmaxf(acc[4][rg] + bias[4], 0.f));
            pk1.y = f32_to_bf16(fmaxf(acc[5][rg] + bias[5], 0.f));
            pk1.z = f32_to_bf16(fmaxf(acc[6][rg] + bias[6], 0.f));
            pk1.w = f32_to_bf16(fmaxf(acc[7][rg] + bias[7], 0.f));
            *(ushort4*)(h + (size_t)e * EHID + 4 * r) = pk0;
            *(ushort4*)(h + (size_t)e * EHID + 64 + 4 * r) = pk1;
        }
    } else if (b < nbN + nbE + nbB) {
        // BmatT: epilogue-pack perm (128-group main / 64-group bias) + T'' layout + h-perm sigma
        int t = (b - nbN - nbE) * 256 + tid;
        if (t >= TC * 64) return;
        int c = t >> 6, i = t & 63;
        int m;
        if (c < 8192) {
            int g = c & 127;                       // mfma col nt*16+r -> mem col 8r+nt
            m = (c & ~127) + 8 * (g & 15) + (g >> 4);
        } else {
            int g = c & 63;                        // bias block keeps 4r+nt
            m = (c & ~63) + 4 * (g & 15) + (g >> 4);
        }
        float v;
        if (m < 8192) {
            int p = ((m >> 11) << 5) | (m & 31);                     // stored h position
            int k = (p & 64) + ((p & 3) << 4) + ((p >> 2) & 15);     // true h channel
            int o = (m >> 5) & 63;
            v = We2[k * HH + i * 64 + o];
        } else {
            v = be2[i * 64 + (m - 8192)];
        }
        BmatT[t] = f32_to_bf16(v);
    } else {
        // histogram src and dst
        int e = (b - nbN - nbE - nbB) * 256 + tid;
        if (e >= n_edges) return;
        atomicAdd(&cntS[src[e]], 1);
        atomicAdd(&cntD[dst[e]], 1);
    }
}

// T[n, m] = sum_i x[n,i]*B[i,m], bf16 out in T'' layout.
// Main path (blockIdx.x<16): wave = 128-col group, 8 B-tiles in regs, lane packs
// 8 bf16 -> one 16-B store. Tail block 16: 64 bias cols, 4r+nt packing.
__global__ void k_T(const unsigned short* __restrict__ outbf, const unsigned short* __restrict__ BmatT,
                    unsigned short* __restrict__ T, int n0, int n1) {
    int wave = threadIdx.x >> 6, lane = threadIdx.x & 63;
    int r = lane & 15, q = lane >> 4;
    int eb = n0 + blockIdx.y * 128;
    if (blockIdx.x < 16) {
        int cb = blockIdx.x * 512 + wave * 128;
        bf16x8 bfr[8][2];
#pragma unroll
        for (int nt = 0; nt < 8; ++nt) {
            size_t cofs = (size_t)(cb + nt * 16 + r) * 64;
            bfr[nt][0] = *(const bf16x8*)(BmatT + cofs + q * 8);
            bfr[nt][1] = *(const bf16x8*)(BmatT + cofs + 32 + q * 8);
        }
#pragma unroll
        for (int mt = 0; mt < 8; ++mt) {
            int e = eb + mt * 16 + r;
            if (e >= n1) e = n1 - 1;
            bf16x8 afr0 = *(const bf16x8*)(outbf + (size_t)e * 64 + q * 8);
            bf16x8 afr1 = *(const bf16x8*)(outbf + (size_t)e * 64 + 32 + q * 8);
            f32x4 acc[8];
#pragma unroll
            for (int nt = 0; nt < 8; ++nt) {
                acc[nt] = __builtin_amdgcn_mfma_f32_16x16x32_bf16(afr0, bfr[nt][0], (f32x4){}, 0, 0, 0);
                acc[nt] = __builtin_amdgcn_mfma_f32_16x16x32_bf16(afr1, bfr[nt][1], acc[nt], 0, 0, 0);
            }
#pragma unroll
            for (int rg = 0; rg < 4; ++rg) {
                int n = eb + mt * 16 + q * 4 + rg;   // C/D: col=lane&15, row=quad*4+reg
                if (n >= n1) continue;
                ushort4 pa, pb;
                pa.x = f32_to_bf16(acc[0][rg]); pa.y = f32_to_bf16(acc[1][rg]);
                pa.z = f32_to_bf16(acc[2][rg]); pa.w = f32_to_bf16(acc[3][rg]);
                pb.x = f32_to_bf16(acc[4][rg]); pb.y = f32_to_bf16(acc[5][rg]);
                pb.z = f32_to_bf16(acc[6][rg]); pb.w = f32_to_bf16(acc[7][rg]);
                uint4 pk = { ((uint32_t)pa.y << 16) | pa.x, ((uint32_t)pa.w << 16) | pa.z,
                             ((uint32_t)pb.y << 16) | pb.x, ((uint32_t)pb.w << 16) | pb.z };
                *(uint4*)(T + (size_t)(n - n0) * TC + cb + 8 * r) = pk;
            }
        }
    } else {
        if (wave != 0) return;               // bias tail: 64 cols only
        int cb = 8192;
        bf16x8 bfr[4][2];
#pragma unroll
        for (int nt = 0; nt < 4; ++nt) {
            size_t cofs = (size_t)(cb + nt * 16 + r) * 64;
            bfr[nt][0] = *(const bf16x8*)(BmatT + cofs + q * 8);
            bfr[nt][1] = *(const bf16x8*)(BmatT + cofs + 32 + q * 8);
        }
#pragma unroll
        for (int mt = 0; mt < 8; ++mt) {
            int e = eb + mt * 16 + r;
            if (e >= n1) e = n1 - 1;
            bf16x8 afr0 = *(const bf16x8*)(outbf + (size_t)e * 64 + q * 8);
            bf16x8 afr1 = *(const bf16x8*)(outbf + (size_t)e * 64 + 32 + q * 8);
            f32x4 acc[4];
#pragma unroll
            for (int nt = 0; nt < 4; ++nt) {
                acc[nt] = __builtin_amdgcn_mfma_f32_16x16x32_bf16(afr0, bfr[nt][0], (f32x4){}, 0, 0, 0);
                acc[nt] = __builtin_amdgcn_mfma_f32_16x16x32_bf16(afr1, bfr[nt][1], acc[nt], 0, 0, 0);
            }
#pragma unroll
            for (int rg = 0; rg < 4; ++rg) {
                int n = eb + mt * 16 + q * 4 + rg;
                if (n >= n1) continue;
                ushort4 pk;
                pk.x = f32_to_bf16(acc[0][rg]);
                pk.y = f32_to_bf16(acc[1][rg]);
                pk.z = f32_to_bf16(acc[2][rg]);
                pk.w = f32_to_bf16(acc[3][rg]);
                *(ushort4*)(T + (size_t)(n - n0) * TC + cb + 4 * r) = pk;
            }
        }
    }
}

// per src-node wave, MFMA: msg[tile of 16 edges][64 o] = h[edges, 0:128] @ T''[n]
// msg stored col-permuted: mem col 4r+nt holds mfma col nt*16+r (16-B f32x4 stores);
// k_agg applies the inverse perm.
__global__ void k_msg(const unsigned short* __restrict__ h, const unsigned short* __restrict__ T,
                      const int* __restrict__ offS, const int* __restrict__ permS,
                      float* __restrict__ msg, int n0, int n1) {
    int wave = threadIdx.x >> 6, lane = threadIdx.x & 63;
    int n = n0 + blockIdx.x * 4 + wave;
    if (n >= n1) return;
    int beg = offS[n], end = offS[n + 1];
    if (beg == end) return;
    int r = lane & 15, q = lane >> 4;
    const unsigned short* Tb = T + (size_t)(n - n0) * TC;
    float bias[4];
#pragma unroll
    for (int nt = 0; nt < 4; ++nt)
        bias[nt] = bfu_to_f(Tb[8192 + nt * 16 + r]);
    for (int j0 = beg; j0 < end; j0 += 16) {
        int jc = j0 + r; if (jc >= end) jc = end - 1;
        int e = permS[jc];
        const unsigned short* he = h + (size_t)e * EHID;
        f32x4 acc[4] = {};
#pragma unroll
        for (int s = 0; s < 4; ++s) {        // K = 128 = 4*32
            bf16x8 afr = *(const bf16x8*)(he + s * 32 + q * 8);
#pragma unroll
            for (int nt = 0; nt < 4; ++nt) {
                bf16x8 bfr = *(const bf16x8*)(Tb + s * 2048 + (nt * 16 + r) * 32 + q * 8);
                acc[nt] = __builtin_amdgcn_mfma_f32_16x16x32_bf16(afr, bfr, acc[nt], 0, 0, 0);
            }
        }
#pragma unroll
        for (int rg = 0; rg < 4; ++rg) {
            int jr = j0 + q * 4 + rg;
            if (jr >= end) continue;
            int er = permS[jr];
            f32x4 pk = { acc[0][rg] + bias[0], acc[1][rg] + bias[1],
                         acc[2][rg] + bias[2], acc[3][rg] + bias[3] };
            *(f32x4*)(msg + (size_t)er * 64 + 4 * r) = pk;
        }
    }
}

// exclusive prefix sum (one block per array; blockIdx.x: 0=S, 1=D)
__global__ void k_scan(const int* __restrict__ cntS, const int* __restrict__ cntD,
                       int* __restrict__ offS, int* __restrict__ offD,
                       int* __restrict__ curS, int* __restrict__ curD, int n, int total) {
    const int* cnt = blockIdx.x ? cntD : cntS;
    int* off = blockIdx.x ? offD : offS;
    int* cur = blockIdx.x ? curD : curS;
    __shared__ int part[256];
    int tid = threadIdx.x;
    int chunk = (n + 255) / 256;
    int c0 = tid * chunk, c1 = c0 + chunk; if (c1 > n) c1 = n; if (c0 > n) c0 = n;
    int s = 0;
    for (int i = c0; i < c1; ++i) s += cnt[i];
    part[tid] = s;
    __syncthreads();
    for (int st = 1; st < 256; st <<= 1) {
        int v = (tid >= st) ? part[tid - st] : 0;
        __syncthreads();
        part[tid] += v;
        __syncthreads();
    }
    int run = tid ? part[tid - 1] : 0;
    for (int i = c0; i < c1; ++i) { off[i] = run; cur[i] = run; run += cnt[i]; }
    if (tid == 0) off[n] = total;
}

__global__ void k_perm(const int* __restrict__ src, const int* __restrict__ dst,
                       int* __restrict__ curS, int* __restrict__ curD,
                       int* __restrict__ permS, int* __restrict__ permD, int n_edges) {
    int e = blockIdx.x * 256 + threadIdx.x;
    if (e >= n_edges) return;
    permS[atomicAdd(&curS[src[e]], 1)] = e;
    permD[atomicAdd(&curD[dst[e]], 1)] = e;
}

// per dst-node wave: out[d] = relu(sum msg + cbias); atomic-free.
// msg cols stored permuted: lane's stored col l is semantic o=(l&3)*16+(l>>2).
// If stat != null (last step): also block-reduce BN sums into stat (semantic index).
__global__ void k_agg(const float* __restrict__ msg, const int* __restrict__ offD,
                      const int* __restrict__ permD, const float* __restrict__ cbias,
                      float* __restrict__ outb, unsigned short* __restrict__ outbf,
                      float* __restrict__ stat, int n_nodes) {
    __shared__ float s1[256], s2[256];
    int wave = threadIdx.x >> 6, lane = threadIdx.x & 63;
    int d = blockIdx.x * 4 + wave;
    int o = (lane & 3) * 16 + (lane >> 2);
    float v = 0.f;
    if (d < n_nodes) {
        float acc = 0.f;
        int end = offD[d + 1];
        for (int j = offD[d]; j < end; ++j)
            acc += msg[(size_t)permD[j] * 64 + lane];
        v = fmaxf(acc + cbias[o], 0.f);
        outb[(size_t)d * 64 + o] = v;
        outbf[(size_t)d * 64 + o] = f32_to_bf16(v);
    }
    if (stat) {
        int tid = threadIdx.x;
        s1[tid] = v; s2[tid] = v * v;
        __syncthreads();
        if (tid < 64) {
            float A = s1[tid] + s1[64 + tid] + s1[128 + tid] + s1[192 + tid];
            float B = s2[tid] + s2[64 + tid] + s2[128 + tid] + s2[192 + tid];
            int os = (tid & 3) * 16 + (tid >> 2);   // semantic feature of stored col tid
            atomicAdd(&stat[os], A);
            atomicAdd(&stat[64 + os], B);
        }
    }
}

// bn_final fused in: every thread derives scale/shift from stat (identical arith)
__global__ void k_bn_apply(const float* __restrict__ out, const float* __restrict__ stat,
                           const float* __restrict__ gamma, const float* __restrict__ beta,
                           float* __restrict__ y, int n, int n_nodes) {
    int t = blockIdx.x * 256 + threadIdx.x;
    if (t >= n) return;
    int f = t & 63;
    float mean = stat[f] / n_nodes;
    float var  = stat[64 + f] / n_nodes - mean * mean;   // population var
    float inv  = rsqrtf(var + 1e-5f);
    float scale = gamma[f] * inv;
    float shift = beta[f] - mean * scale;
    y[t] = out[t] * scale + shift;
}

extern "C" void kernel_launch(void* const* d_in, const int* in_sizes, int n_in,
                              void* d_out, int out_size, void* d_ws, size_t ws_size,
                              hipStream_t stream) {
    const float* nf    = (const float*)d_in[0];
    const float* ef    = (const float*)d_in[1];
    const int*   src   = (const int*)d_in[2];
    const int*   dst   = (const int*)d_in[3];
    const float* W0    = (const float*)d_in[4];
    const float* b0    = (const float*)d_in[5];
    const float* We1   = (const float*)d_in[6];
    const float* be1   = (const float*)d_in[7];
    const float* We2   = (const float*)d_in[8];
    const float* be2   = (const float*)d_in[9];
    const float* cbias = (const float*)d_in[10];
    const float* gamma = (const float*)d_in[11];
    const float* beta  = (const float*)d_in[12];
    (void)n_in; (void)out_size;

    int n_nodes = in_sizes[0] / DIN;   // 10000
    int n_edges = in_sizes[2];         // 100000

    char* ws = (char*)d_ws;
    size_t off = 0;
    auto carve = [&](size_t bytes) -> void* {
        void* p = ws + off;
        off = (off + bytes + 255) & ~(size_t)255;
        return p;
    };
    unsigned short* h     = (unsigned short*)carve((size_t)n_edges * EHID * 2);  // 25.6 MB
    float*          msg   = (float*)carve((size_t)n_edges * 64 * 4);             // 25.6 MB
    float*          outb  = (float*)carve((size_t)n_nodes * HDIM * 4);
    unsigned short* outbf = (unsigned short*)carve((size_t)n_nodes * HDIM * 2);
    unsigned short* BmatT = (unsigned short*)carve((size_t)TC * 64 * 2);
    int*            offS  = (int*)carve((size_t)(n_nodes + 1) * 4);
    int*            offD  = (int*)carve((size_t)(n_nodes + 1) * 4);
    int*            curS  = (int*)carve((size_t)n_nodes * 4);
    int*            curD  = (int*)carve((size_t)n_nodes * 4);
    int*            permS = (int*)carve((size_t)n_edges * 4);
    int*            permD = (int*)carve((size_t)n_edges * 4);
    float*          stat  = (float*)carve(128 * 4 + (size_t)2 * n_nodes * 4); // stat + cntS + cntD
    int*            cntS  = (int*)(stat + 128);
    int*            cntD  = cntS + n_nodes;
    unsigned short* T     = (unsigned short*)(ws + off);
    size_t avail = ws_size > off ? ws_size - off : 0;
    long tcap = (long)(avail / ((size_t)TC * 2));   // ws-capacity bound (node rows)
    if (tcap > n_nodes) tcap = n_nodes;
    if (tcap < 64) tcap = 64;
    long tchunk = tcap;   // R7: chunking measured neutral -> single chunk, fewer launches

    hipMemsetAsync(stat, 0, 128 * 4 + (size_t)2 * n_nodes * 4, stream);

    int nbN = (n_nodes + 3) / 4;            // 2500
    int nbE = (n_edges + 63) / 64;          // 1563 (MFMA edge path: 64 edges/block)
    int nbB = (TC * 64 + 255) / 256;        // 2064
    int nbH = (n_edges + 255) / 256;        // 391
    k_pro<<<dim3(nbN + nbE + nbB + nbH), 256, 0, stream>>>(
        nf, W0, b0, outb, outbf, ef, We1, be1, h, We2, be2, BmatT,
        src, dst, cntS, cntD, n_nodes, n_edges, nbN, nbE, nbB);
    k_scan<<<dim3(2), 256, 0, stream>>>(cntS, cntD, offS, offD, curS, curD, n_nodes, n_edges);
    k_perm<<<dim3((n_edges + 255) / 256), 256, 0, stream>>>(src, dst, curS, curD, permS, permD, n_edges);

    for (int step = 0; step < STEPS; ++step) {
        for (long n0 = 0; n0 < n_nodes; n0 += tchunk) {
            long n1 = n0 + tchunk; if (n1 > n_nodes) n1 = n_nodes;
            long cnt = n1 - n0;
            k_T<<<dim3(17, (cnt + 127) / 128), 256, 0, stream>>>(
                outbf, BmatT, T, (int)n0, (int)n1);
            k_msg<<<dim3((cnt + 3) / 4), 256, 0, stream>>>(
                h, T, offS, permS, msg, (int)n0, (int)n1);
        }
        k_agg<<<dim3((n_nodes + 3) / 4), 256, 0, stream>>>(
            msg, offD, permD, cbias, outb, outbf,
            (step == STEPS - 1) ? stat : (float*)nullptr, n_nodes);
    }

    k_bn_apply<<<dim3((n_nodes * HDIM + 255) / 256), 256, 0, stream>>>(
        outb, stat, gamma, beta, (float*)d_out, n_nodes * HDIM, n_nodes);
}

// Round 14
// 442.764 us; speedup vs baseline: 1.2767x; 1.0528x over previous
//
#include <hip/hip_runtime.h>
#include <stdint.h>

#define DIN   64
#define HDIM  64
#define EIN   16
#define EHID  128     // edge hidden width
#define HH    4096    // HDIM*HDIM
#define TC    8256    // T cols: 8192 main + 64 bias
#define STEPS 3

typedef short bf16x8 __attribute__((ext_vector_type(8)));
typedef float f32x4  __attribute__((ext_vector_type(4)));

__device__ __forceinline__ unsigned short f32_to_bf16(float f) {
    union { float f; uint32_t u; } v; v.f = f;
    uint32_t r = v.u + 0x7fffu + ((v.u >> 16) & 1u);   // RNE
    return (unsigned short)(r >> 16);
}
__device__ __forceinline__ float bfu_to_f(unsigned short u) {
    union { uint32_t u; float f; } v; v.u = (uint32_t)u << 16; return v.f;
}

// ---- merged prologue: [0,nbN) node_mlp | [nbN,+nbE) edge_mlp(MFMA) | [+nbB) bmat | rest hist ----
__global__ void k_pro(const float* __restrict__ nf, const float* __restrict__ W0,
                      const float* __restrict__ b0, float* __restrict__ outb,
                      unsigned short* __restrict__ outbf,
                      const float* __restrict__ ef, const float* __restrict__ We1,
                      const float* __restrict__ be1, unsigned short* __restrict__ h,
                      const float* __restrict__ We2, const float* __restrict__ be2,
                      unsigned short* __restrict__ BmatT,
                      const int* __restrict__ src, const int* __restrict__ dst,
                      int* __restrict__ cntS, int* __restrict__ cntD,
                      int n_nodes, int n_edges, int nbN, int nbE, int nbB) {
    __shared__ float smem[DIN * HDIM];   // 16 KB (node path only)
    int b = blockIdx.x, tid = threadIdx.x;
    if (b < nbN) {
        // node MLP: out[n,o] = relu(n_feat[n,:]@W0[:,o]+b0[o]); 4 nodes/block
        for (int i = tid; i < DIN * HDIM; i += 256) smem[i] = W0[i];
        __syncthreads();
        int node = b * 4 + (tid >> 6);
        int o = tid & 63;
        if (node >= n_nodes) return;
        float xr = nf[node * DIN + o];
        float acc = b0[o];
#pragma unroll 8
        for (int i = 0; i < DIN; ++i)
            acc += __shfl(xr, i, 64) * smem[i * HDIM + o];
        float v = fmaxf(acc, 0.f);
        outb[node * HDIM + o] = v;
        outbf[node * HDIM + o] = f32_to_bf16(v);
    } else if (b < nbN + nbE) {
        // edge MLP via MFMA: 64 edges/block (16/wave), K=16 zero-padded to 32.
        // h stored with per-64-group col perm sigma (inverse baked into BmatT k-index).
        int wave = tid >> 6, lane = tid & 63;
        int r = lane & 15, q = lane >> 4;
        int e0 = (b - nbN) * 64 + wave * 16;
        if (e0 >= n_edges) return;           // wave-uniform
        bf16x8 afr = (bf16x8){};
        bf16x8 bfr[8];
#pragma unroll
        for (int nt = 0; nt < 8; ++nt) bfr[nt] = (bf16x8){};
        if (q < 2) {
            int ea = e0 + r; if (ea >= n_edges) ea = n_edges - 1;
            const float* xa = ef + (size_t)ea * EIN + q * 8;
#pragma unroll
            for (int j = 0; j < 8; ++j) afr[j] = (short)f32_to_bf16(xa[j]);
#pragma unroll
            for (int nt = 0; nt < 8; ++nt)
#pragma unroll
                for (int j = 0; j < 8; ++j)
                    bfr[nt][j] = (short)f32_to_bf16(We1[(q * 8 + j) * EHID + nt * 16 + r]);
        }
        f32x4 acc[8];
#pragma unroll
        for (int nt = 0; nt < 8; ++nt)
            acc[nt] = __builtin_amdgcn_mfma_f32_16x16x32_bf16(afr, bfr[nt], (f32x4){}, 0, 0, 0);
        float bias[8];
#pragma unroll
        for (int nt = 0; nt < 8; ++nt) bias[nt] = be1[nt * 16 + r];
#pragma unroll
        for (int rg = 0; rg < 4; ++rg) {
            int e = e0 + q * 4 + rg;         // C/D: col=lane&15, row=quad*4+reg
            if (e >= n_edges) continue;
            ushort4 pk0, pk1;
            pk0.x = f32_to_bf16(fmaxf(acc[0][rg] + bias[0], 0.f));
            pk0.y = f32_to_bf16(fmaxf(acc[1][rg] + bias[1], 0.f));
            pk0.z = f32_to_bf16(fmaxf(acc[2][rg] + bias[2], 0.f));
            pk0.w = f32_to_bf16(fmaxf(acc[3][rg] + bias[3], 0.f));
            pk1.x = f32_to_bf16(fmaxf(acc[4][rg] + bias[4], 0.f));
            pk1.y = f32_to_bf16(fmaxf(acc[5][rg] + bias[5], 0.f));
            pk1.z = f32_to_bf16(fmaxf(acc[6][rg] + bias[6], 0.f));
            pk1.w = f32_to_bf16(fmaxf(acc[7][rg] + bias[7], 0.f));
            *(ushort4*)(h + (size_t)e * EHID + 4 * r) = pk0;
            *(ushort4*)(h + (size_t)e * EHID + 64 + 4 * r) = pk1;
        }
    } else if (b < nbN + nbE + nbB) {
        // BmatT: epilogue-pack perm (128-group main / 64-group bias) + T'' layout + h-perm sigma
        int t = (b - nbN - nbE) * 256 + tid;
        if (t >= TC * 64) return;
        int c = t >> 6, i = t & 63;
        int m;
        if (c < 8192) {
            int g = c & 127;                       // mfma col nt*16+r -> mem col 8r+nt
            m = (c & ~127) + 8 * (g & 15) + (g >> 4);
        } else {
            int g = c & 63;                        // bias block keeps 4r+nt
            m = (c & ~63) + 4 * (g & 15) + (g >> 4);
        }
        float v;
        if (m < 8192) {
            int p = ((m >> 11) << 5) | (m & 31);                     // stored h position
            int k = (p & 64) + ((p & 3) << 4) + ((p >> 2) & 15);     // true h channel
            int o = (m >> 5) & 63;
            v = We2[k * HH + i * 64 + o];
        } else {
            v = be2[i * 64 + (m - 8192)];
        }
        BmatT[t] = f32_to_bf16(v);
    } else {
        // histogram src and dst
        int e = (b - nbN - nbE - nbB) * 256 + tid;
        if (e >= n_edges) return;
        atomicAdd(&cntS[src[e]], 1);
        atomicAdd(&cntD[dst[e]], 1);
    }
}

// T[n, m] = sum_i x[n,i]*B[i,m], bf16 out in T'' layout.
// Main path (blockIdx.x<16): wave = 128-col group, 8 B-tiles in regs, lane packs
// 8 bf16 -> one 16-B store. Tail block 16: 64 bias cols, 4r+nt packing.
__global__ void k_T(const unsigned short* __restrict__ outbf, const unsigned short* __restrict__ BmatT,
                    unsigned short* __restrict__ T, int n0, int n1) {
    int wave = threadIdx.x >> 6, lane = threadIdx.x & 63;
    int r = lane & 15, q = lane >> 4;
    int eb = n0 + blockIdx.y * 128;
    if (blockIdx.x < 16) {
        int cb = blockIdx.x * 512 + wave * 128;
        bf16x8 bfr[8][2];
#pragma unroll
        for (int nt = 0; nt < 8; ++nt) {
            size_t cofs = (size_t)(cb + nt * 16 + r) * 64;
            bfr[nt][0] = *(const bf16x8*)(BmatT + cofs + q * 8);
            bfr[nt][1] = *(const bf16x8*)(BmatT + cofs + 32 + q * 8);
        }
#pragma unroll
        for (int mt = 0; mt < 8; ++mt) {
            int e = eb + mt * 16 + r;
            if (e >= n1) e = n1 - 1;
            bf16x8 afr0 = *(const bf16x8*)(outbf + (size_t)e * 64 + q * 8);
            bf16x8 afr1 = *(const bf16x8*)(outbf + (size_t)e * 64 + 32 + q * 8);
            f32x4 acc[8];
#pragma unroll
            for (int nt = 0; nt < 8; ++nt) {
                acc[nt] = __builtin_amdgcn_mfma_f32_16x16x32_bf16(afr0, bfr[nt][0], (f32x4){}, 0, 0, 0);
                acc[nt] = __builtin_amdgcn_mfma_f32_16x16x32_bf16(afr1, bfr[nt][1], acc[nt], 0, 0, 0);
            }
#pragma unroll
            for (int rg = 0; rg < 4; ++rg) {
                int n = eb + mt * 16 + q * 4 + rg;   // C/D: col=lane&15, row=quad*4+reg
                if (n >= n1) continue;
                ushort4 pa, pb;
                pa.x = f32_to_bf16(acc[0][rg]); pa.y = f32_to_bf16(acc[1][rg]);
                pa.z = f32_to_bf16(acc[2][rg]); pa.w = f32_to_bf16(acc[3][rg]);
                pb.x = f32_to_bf16(acc[4][rg]); pb.y = f32_to_bf16(acc[5][rg]);
                pb.z = f32_to_bf16(acc[6][rg]); pb.w = f32_to_bf16(acc[7][rg]);
                uint4 pk = { ((uint32_t)pa.y << 16) | pa.x, ((uint32_t)pa.w << 16) | pa.z,
                             ((uint32_t)pb.y << 16) | pb.x, ((uint32_t)pb.w << 16) | pb.z };
                *(uint4*)(T + (size_t)(n - n0) * TC + cb + 8 * r) = pk;
            }
        }
    } else {
        if (wave != 0) return;               // bias tail: 64 cols only
        int cb = 8192;
        bf16x8 bfr[4][2];
#pragma unroll
        for (int nt = 0; nt < 4; ++nt) {
            size_t cofs = (size_t)(cb + nt * 16 + r) * 64;
            bfr[nt][0] = *(const bf16x8*)(BmatT + cofs + q * 8);
            bfr[nt][1] = *(const bf16x8*)(BmatT + cofs + 32 + q * 8);
        }
#pragma unroll
        for (int mt = 0; mt < 8; ++mt) {
            int e = eb + mt * 16 + r;
            if (e >= n1) e = n1 - 1;
            bf16x8 afr0 = *(const bf16x8*)(outbf + (size_t)e * 64 + q * 8);
            bf16x8 afr1 = *(const bf16x8*)(outbf + (size_t)e * 64 + 32 + q * 8);
            f32x4 acc[4];
#pragma unroll
            for (int nt = 0; nt < 4; ++nt) {
                acc[nt] = __builtin_amdgcn_mfma_f32_16x16x32_bf16(afr0, bfr[nt][0], (f32x4){}, 0, 0, 0);
                acc[nt] = __builtin_amdgcn_mfma_f32_16x16x32_bf16(afr1, bfr[nt][1], acc[nt], 0, 0, 0);
            }
#pragma unroll
            for (int rg = 0; rg < 4; ++rg) {
                int n = eb + mt * 16 + q * 4 + rg;
                if (n >= n1) continue;
                ushort4 pk;
                pk.x = f32_to_bf16(acc[0][rg]);
                pk.y = f32_to_bf16(acc[1][rg]);
                pk.z = f32_to_bf16(acc[2][rg]);
                pk.w = f32_to_bf16(acc[3][rg]);
                *(ushort4*)(T + (size_t)(n - n0) * TC + cb + 4 * r) = pk;
            }
        }
    }
}

// per src-node wave, MFMA: msg[tile of 16 edges][64 o] = h[edges, 0:128] @ T''[n]
// msg stored col-permuted: mem col 4r+nt holds mfma col nt*16+r (16-B f32x4 stores);
// k_agg applies the inverse perm. Rows indexed by EDGE ID (validated R12 layout).
__global__ void k_msg(const unsigned short* __restrict__ h, const unsigned short* __restrict__ T,
                      const int* __restrict__ offS, const int* __restrict__ permS,
                      float* __restrict__ msg, int n0, int n1) {
    int wave = threadIdx.x >> 6, lane = threadIdx.x & 63;
    int n = n0 + blockIdx.x * 4 + wave;
    if (n >= n1) return;
    int beg = offS[n], end = offS[n + 1];
    if (beg == end) return;
    int r = lane & 15, q = lane >> 4;
    const unsigned short* Tb = T + (size_t)(n - n0) * TC;
    float bias[4];
#pragma unroll
    for (int nt = 0; nt < 4; ++nt)
        bias[nt] = bfu_to_f(Tb[8192 + nt * 16 + r]);
    for (int j0 = beg; j0 < end; j0 += 16) {
        int jc = j0 + r; if (jc >= end) jc = end - 1;
        int e = permS[jc];
        const unsigned short* he = h + (size_t)e * EHID;
        f32x4 acc[4] = {};
#pragma unroll
        for (int s = 0; s < 4; ++s) {        // K = 128 = 4*32
            bf16x8 afr = *(const bf16x8*)(he + s * 32 + q * 8);
#pragma unroll
            for (int nt = 0; nt < 4; ++nt) {
                bf16x8 bfr = *(const bf16x8*)(Tb + s * 2048 + (nt * 16 + r) * 32 + q * 8);
                acc[nt] = __builtin_amdgcn_mfma_f32_16x16x32_bf16(afr, bfr, acc[nt], 0, 0, 0);
            }
        }
#pragma unroll
        for (int rg = 0; rg < 4; ++rg) {
            int jr = j0 + q * 4 + rg;
            if (jr >= end) continue;
            int er = permS[jr];
            f32x4 pk = { acc[0][rg] + bias[0], acc[1][rg] + bias[1],
                         acc[2][rg] + bias[2], acc[3][rg] + bias[3] };
            *(f32x4*)(msg + (size_t)er * 64 + 4 * r) = pk;
        }
    }
}

// exclusive prefix sum (one block per array; blockIdx.x: 0=S, 1=D)
__global__ void k_scan(const int* __restrict__ cntS, const int* __restrict__ cntD,
                       int* __restrict__ offS, int* __restrict__ offD,
                       int* __restrict__ curS, int* __restrict__ curD, int n, int total) {
    const int* cnt = blockIdx.x ? cntD : cntS;
    int* off = blockIdx.x ? offD : offS;
    int* cur = blockIdx.x ? curD : curS;
    __shared__ int part[256];
    int tid = threadIdx.x;
    int chunk = (n + 255) / 256;
    int c0 = tid * chunk, c1 = c0 + chunk; if (c1 > n) c1 = n; if (c0 > n) c0 = n;
    int s = 0;
    for (int i = c0; i < c1; ++i) s += cnt[i];
    part[tid] = s;
    __syncthreads();
    for (int st = 1; st < 256; st <<= 1) {
        int v = (tid >= st) ? part[tid - st] : 0;
        __syncthreads();
        part[tid] += v;
        __syncthreads();
    }
    int run = tid ? part[tid - 1] : 0;
    for (int i = c0; i < c1; ++i) { off[i] = run; cur[i] = run; run += cnt[i]; }
    if (tid == 0) off[n] = total;
}

__global__ void k_perm(const int* __restrict__ src, const int* __restrict__ dst,
                       int* __restrict__ curS, int* __restrict__ curD,
                       int* __restrict__ permS, int* __restrict__ permD, int n_edges) {
    int e = blockIdx.x * 256 + threadIdx.x;
    if (e >= n_edges) return;
    permS[atomicAdd(&curS[src[e]], 1)] = e;
    permD[atomicAdd(&curD[dst[e]], 1)] = e;
}

// per dst-node wave: out[d] = relu(sum msg + cbias); atomic-free gather,
// SOFTWARE-PIPELINED: 16 lane-uniform index loads then 16 independent row
// loads in flight (R12 profile showed serial 1-outstanding codegen, 69.5 us).
// msg cols stored permuted: lane's stored col l is semantic o=(l&3)*16+(l>>2).
// If stat != null (last step): block-reduce BN sums into stat (semantic index).
__global__ void k_agg(const float* __restrict__ msg, const int* __restrict__ offD,
                      const int* __restrict__ permD, const float* __restrict__ cbias,
                      float* __restrict__ outb, unsigned short* __restrict__ outbf,
                      float* __restrict__ stat, int n_nodes) {
    __shared__ float s1[256], s2[256];
    int wave = threadIdx.x >> 6, lane = threadIdx.x & 63;
    int d = blockIdx.x * 4 + wave;
    int o = (lane & 3) * 16 + (lane >> 2);
    float v = 0.f;
    if (d < n_nodes) {
        int beg = offD[d], end = offD[d + 1];
        float acc = 0.f;
        for (int j0 = beg; j0 < end; j0 += 16) {
            int nrem = end - j0;               // >= 1
            int idx[16];
#pragma unroll
            for (int k = 0; k < 16; ++k) {
                int jj = j0 + k; if (jj >= end) jj = j0;
                idx[k] = permD[jj];            // lane-uniform -> scalarized
            }
            float vals[16];
#pragma unroll
            for (int k = 0; k < 16; ++k)
                vals[k] = msg[(size_t)idx[k] * 64 + lane];   // 16 independent loads
#pragma unroll
            for (int k = 0; k < 16; ++k)
                if (k < nrem) acc += vals[k];
        }
        v = fmaxf(acc + cbias[o], 0.f);
        outb[(size_t)d * 64 + o] = v;
        outbf[(size_t)d * 64 + o] = f32_to_bf16(v);
    }
    if (stat) {
        int tid = threadIdx.x;
        s1[tid] = v; s2[tid] = v * v;
        __syncthreads();
        if (tid < 64) {
            float A = s1[tid] + s1[64 + tid] + s1[128 + tid] + s1[192 + tid];
            float B = s2[tid] + s2[64 + tid] + s2[128 + tid] + s2[192 + tid];
            int os = (tid & 3) * 16 + (tid >> 2);   // semantic feature of stored col tid
            atomicAdd(&stat[os], A);
            atomicAdd(&stat[64 + os], B);
        }
    }
}

// bn_final fused in: every thread derives scale/shift from stat (identical arith)
__global__ void k_bn_apply(const float* __restrict__ out, const float* __restrict__ stat,
                           const float* __restrict__ gamma, const float* __restrict__ beta,
                           float* __restrict__ y, int n, int n_nodes) {
    int t = blockIdx.x * 256 + threadIdx.x;
    if (t >= n) return;
    int f = t & 63;
    float mean = stat[f] / n_nodes;
    float var  = stat[64 + f] / n_nodes - mean * mean;   // population var
    float inv  = rsqrtf(var + 1e-5f);
    float scale = gamma[f] * inv;
    float shift = beta[f] - mean * scale;
    y[t] = out[t] * scale + shift;
}

extern "C" void kernel_launch(void* const* d_in, const int* in_sizes, int n_in,
                              void* d_out, int out_size, void* d_ws, size_t ws_size,
                              hipStream_t stream) {
    const float* nf    = (const float*)d_in[0];
    const float* ef    = (const float*)d_in[1];
    const int*   src   = (const int*)d_in[2];
    const int*   dst   = (const int*)d_in[3];
    const float* W0    = (const float*)d_in[4];
    const float* b0    = (const float*)d_in[5];
    const float* We1   = (const float*)d_in[6];
    const float* be1   = (const float*)d_in[7];
    const float* We2   = (const float*)d_in[8];
    const float* be2   = (const float*)d_in[9];
    const float* cbias = (const float*)d_in[10];
    const float* gamma = (const float*)d_in[11];
    const float* beta  = (const float*)d_in[12];
    (void)n_in; (void)out_size;

    int n_nodes = in_sizes[0] / DIN;   // 10000
    int n_edges = in_sizes[2];         // 100000

    char* ws = (char*)d_ws;
    size_t off = 0;
    auto carve = [&](size_t bytes) -> void* {
        void* p = ws + off;
        off = (off + bytes + 255) & ~(size_t)255;
        return p;
    };
    unsigned short* h     = (unsigned short*)carve((size_t)n_edges * EHID * 2);  // 25.6 MB
    float*          msg   = (float*)carve((size_t)n_edges * 64 * 4);             // 25.6 MB
    float*          outb  = (float*)carve((size_t)n_nodes * HDIM * 4);
    unsigned short* outbf = (unsigned short*)carve((size_t)n_nodes * HDIM * 2);
    unsigned short* BmatT = (unsigned short*)carve((size_t)TC * 64 * 2);
    int*            offS  = (int*)carve((size_t)(n_nodes + 1) * 4);
    int*            offD  = (int*)carve((size_t)(n_nodes + 1) * 4);
    int*            curS  = (int*)carve((size_t)n_nodes * 4);
    int*            curD  = (int*)carve((size_t)n_nodes * 4);
    int*            permS = (int*)carve((size_t)n_edges * 4);
    int*            permD = (int*)carve((size_t)n_edges * 4);
    float*          stat  = (float*)carve(128 * 4 + (size_t)2 * n_nodes * 4); // stat + cntS + cntD
    int*            cntS  = (int*)(stat + 128);
    int*            cntD  = cntS + n_nodes;
    unsigned short* T     = (unsigned short*)(ws + off);
    size_t avail = ws_size > off ? ws_size - off : 0;
    long tcap = (long)(avail / ((size_t)TC * 2));   // ws-capacity bound (node rows)
    if (tcap > n_nodes) tcap = n_nodes;
    if (tcap < 64) tcap = 64;
    long tchunk = tcap;   // single chunk with current ws

    hipMemsetAsync(stat, 0, 128 * 4 + (size_t)2 * n_nodes * 4, stream);

    int nbN = (n_nodes + 3) / 4;            // 2500
    int nbE = (n_edges + 63) / 64;          // 1563 (MFMA edge path: 64 edges/block)
    int nbB = (TC * 64 + 255) / 256;        // 2064
    int nbH = (n_edges + 255) / 256;        // 391
    k_pro<<<dim3(nbN + nbE + nbB + nbH), 256, 0, stream>>>(
        nf, W0, b0, outb, outbf, ef, We1, be1, h, We2, be2, BmatT,
        src, dst, cntS, cntD, n_nodes, n_edges, nbN, nbE, nbB);
    k_scan<<<dim3(2), 256, 0, stream>>>(cntS, cntD, offS, offD, curS, curD, n_nodes, n_edges);
    k_perm<<<dim3((n_edges + 255) / 256), 256, 0, stream>>>(src, dst, curS, curD, permS, permD, n_edges);

    for (int step = 0; step < STEPS; ++step) {
        for (long n0 = 0; n0 < n_nodes; n0 += tchunk) {
            long n1 = n0 + tchunk; if (n1 > n_nodes) n1 = n_nodes;
            long cnt = n1 - n0;
            k_T<<<dim3(17, (cnt + 127) / 128), 256, 0, stream>>>(
                outbf, BmatT, T, (int)n0, (int)n1);
            k_msg<<<dim3((cnt + 3) / 4), 256, 0, stream>>>(
                h, T, offS, permS, msg, (int)n0, (int)n1);
        }
        k_agg<<<dim3((n_nodes + 3) / 4), 256, 0, stream>>>(
            msg, offD, permD, cbias, outb, outbf,
            (step == STEPS - 1) ? stat : (float*)nullptr, n_nodes);
    }

    k_bn_apply<<<dim3((n_nodes * HDIM + 255) / 256), 256, 0, stream>>>(
        outb, stat, gamma, beta, (float*)d_out, n_nodes * HDIM, n_nodes);
}

// Round 15
// 438.559 us; speedup vs baseline: 1.2890x; 1.0096x over previous
//
#include <hip/hip_runtime.h>
#include <stdint.h>

#define DIN   64
#define HDIM  64
#define EIN   16
#define EHID  128     // edge hidden width
#define HH    4096    // HDIM*HDIM
#define TC    8256    // T cols: 8192 main + 64 bias
#define STEPS 3

typedef short bf16x8 __attribute__((ext_vector_type(8)));
typedef float f32x4  __attribute__((ext_vector_type(4)));

__device__ __forceinline__ unsigned short f32_to_bf16(float f) {
    union { float f; uint32_t u; } v; v.f = f;
    uint32_t r = v.u + 0x7fffu + ((v.u >> 16) & 1u);   // RNE
    return (unsigned short)(r >> 16);
}
__device__ __forceinline__ float bfu_to_f(unsigned short u) {
    union { uint32_t u; float f; } v; v.u = (uint32_t)u << 16; return v.f;
}

// ---- merged prologue: [0,nbN) node_mlp | [nbN,+nbE) edge_mlp(MFMA) | [+nbB) bmat | rest hist ----
__global__ void k_pro(const float* __restrict__ nf, const float* __restrict__ W0,
                      const float* __restrict__ b0, float* __restrict__ outb,
                      unsigned short* __restrict__ outbf,
                      const float* __restrict__ ef, const float* __restrict__ We1,
                      const float* __restrict__ be1, unsigned short* __restrict__ h,
                      const float* __restrict__ We2, const float* __restrict__ be2,
                      unsigned short* __restrict__ BmatT,
                      const int* __restrict__ src, const int* __restrict__ dst,
                      int* __restrict__ cntS, int* __restrict__ cntD,
                      int n_nodes, int n_edges, int nbN, int nbE, int nbB) {
    __shared__ float smem[DIN * HDIM];   // 16 KB (node path only)
    int b = blockIdx.x, tid = threadIdx.x;
    if (b < nbN) {
        // node MLP: out[n,o] = relu(n_feat[n,:]@W0[:,o]+b0[o]); 4 nodes/block
        for (int i = tid; i < DIN * HDIM; i += 256) smem[i] = W0[i];
        __syncthreads();
        int node = b * 4 + (tid >> 6);
        int o = tid & 63;
        if (node >= n_nodes) return;
        float xr = nf[node * DIN + o];
        float acc = b0[o];
#pragma unroll 8
        for (int i = 0; i < DIN; ++i)
            acc += __shfl(xr, i, 64) * smem[i * HDIM + o];
        float v = fmaxf(acc, 0.f);
        outb[node * HDIM + o] = v;
        outbf[node * HDIM + o] = f32_to_bf16(v);
    } else if (b < nbN + nbE) {
        // edge MLP via MFMA: 64 edges/block (16/wave), K=16 zero-padded to 32.
        // h stored with per-64-group col perm sigma (inverse baked into BmatT k-index).
        int wave = tid >> 6, lane = tid & 63;
        int r = lane & 15, q = lane >> 4;
        int e0 = (b - nbN) * 64 + wave * 16;
        if (e0 >= n_edges) return;           // wave-uniform
        bf16x8 afr = (bf16x8){};
        bf16x8 bfr[8];
#pragma unroll
        for (int nt = 0; nt < 8; ++nt) bfr[nt] = (bf16x8){};
        if (q < 2) {
            int ea = e0 + r; if (ea >= n_edges) ea = n_edges - 1;
            const float* xa = ef + (size_t)ea * EIN + q * 8;
#pragma unroll
            for (int j = 0; j < 8; ++j) afr[j] = (short)f32_to_bf16(xa[j]);
#pragma unroll
            for (int nt = 0; nt < 8; ++nt)
#pragma unroll
                for (int j = 0; j < 8; ++j)
                    bfr[nt][j] = (short)f32_to_bf16(We1[(q * 8 + j) * EHID + nt * 16 + r]);
        }
        f32x4 acc[8];
#pragma unroll
        for (int nt = 0; nt < 8; ++nt)
            acc[nt] = __builtin_amdgcn_mfma_f32_16x16x32_bf16(afr, bfr[nt], (f32x4){}, 0, 0, 0);
        float bias[8];
#pragma unroll
        for (int nt = 0; nt < 8; ++nt) bias[nt] = be1[nt * 16 + r];
#pragma unroll
        for (int rg = 0; rg < 4; ++rg) {
            int e = e0 + q * 4 + rg;         // C/D: col=lane&15, row=quad*4+reg
            if (e >= n_edges) continue;
            ushort4 pk0, pk1;
            pk0.x = f32_to_bf16(fmaxf(acc[0][rg] + bias[0], 0.f));
            pk0.y = f32_to_bf16(fmaxf(acc[1][rg] + bias[1], 0.f));
            pk0.z = f32_to_bf16(fmaxf(acc[2][rg] + bias[2], 0.f));
            pk0.w = f32_to_bf16(fmaxf(acc[3][rg] + bias[3], 0.f));
            pk1.x = f32_to_bf16(fmaxf(acc[4][rg] + bias[4], 0.f));
            pk1.y = f32_to_bf16(fmaxf(acc[5][rg] + bias[5], 0.f));
            pk1.z = f32_to_bf16(fmaxf(acc[6][rg] + bias[6], 0.f));
            pk1.w = f32_to_bf16(fmaxf(acc[7][rg] + bias[7], 0.f));
            *(ushort4*)(h + (size_t)e * EHID + 4 * r) = pk0;
            *(ushort4*)(h + (size_t)e * EHID + 64 + 4 * r) = pk1;
        }
    } else if (b < nbN + nbE + nbB) {
        // BmatT: epilogue-pack perm (128-group main / 64-group bias) + T'' layout + h-perm sigma
        int t = (b - nbN - nbE) * 256 + tid;
        if (t >= TC * 64) return;
        int c = t >> 6, i = t & 63;
        int m;
        if (c < 8192) {
            int g = c & 127;                       // mfma col nt*16+r -> mem col 8r+nt
            m = (c & ~127) + 8 * (g & 15) + (g >> 4);
        } else {
            int g = c & 63;                        // bias block keeps 4r+nt
            m = (c & ~63) + 4 * (g & 15) + (g >> 4);
        }
        float v;
        if (m < 8192) {
            int p = ((m >> 11) << 5) | (m & 31);                     // stored h position
            int k = (p & 64) + ((p & 3) << 4) + ((p >> 2) & 15);     // true h channel
            int o = (m >> 5) & 63;
            v = We2[k * HH + i * 64 + o];
        } else {
            v = be2[i * 64 + (m - 8192)];
        }
        BmatT[t] = f32_to_bf16(v);
    } else {
        // histogram src and dst
        int e = (b - nbN - nbE - nbB) * 256 + tid;
        if (e >= n_edges) return;
        atomicAdd(&cntS[src[e]], 1);
        atomicAdd(&cntD[dst[e]], 1);
    }
}

// T[n, m] = sum_i x[n,i]*B[i,m], bf16 out in T'' layout.
// Main path (blockIdx.x<16): wave = 128-col group, 8 B-tiles in regs, lane packs
// 8 bf16 -> one 16-B store. Tail block 16: 64 bias cols, 4r+nt packing.
__global__ void k_T(const unsigned short* __restrict__ outbf, const unsigned short* __restrict__ BmatT,
                    unsigned short* __restrict__ T, int n0, int n1) {
    int wave = threadIdx.x >> 6, lane = threadIdx.x & 63;
    int r = lane & 15, q = lane >> 4;
    int eb = n0 + blockIdx.y * 128;
    if (blockIdx.x < 16) {
        int cb = blockIdx.x * 512 + wave * 128;
        bf16x8 bfr[8][2];
#pragma unroll
        for (int nt = 0; nt < 8; ++nt) {
            size_t cofs = (size_t)(cb + nt * 16 + r) * 64;
            bfr[nt][0] = *(const bf16x8*)(BmatT + cofs + q * 8);
            bfr[nt][1] = *(const bf16x8*)(BmatT + cofs + 32 + q * 8);
        }
#pragma unroll
        for (int mt = 0; mt < 8; ++mt) {
            int e = eb + mt * 16 + r;
            if (e >= n1) e = n1 - 1;
            bf16x8 afr0 = *(const bf16x8*)(outbf + (size_t)e * 64 + q * 8);
            bf16x8 afr1 = *(const bf16x8*)(outbf + (size_t)e * 64 + 32 + q * 8);
            f32x4 acc[8];
#pragma unroll
            for (int nt = 0; nt < 8; ++nt) {
                acc[nt] = __builtin_amdgcn_mfma_f32_16x16x32_bf16(afr0, bfr[nt][0], (f32x4){}, 0, 0, 0);
                acc[nt] = __builtin_amdgcn_mfma_f32_16x16x32_bf16(afr1, bfr[nt][1], acc[nt], 0, 0, 0);
            }
#pragma unroll
            for (int rg = 0; rg < 4; ++rg) {
                int n = eb + mt * 16 + q * 4 + rg;   // C/D: col=lane&15, row=quad*4+reg
                if (n >= n1) continue;
                ushort4 pa, pb;
                pa.x = f32_to_bf16(acc[0][rg]); pa.y = f32_to_bf16(acc[1][rg]);
                pa.z = f32_to_bf16(acc[2][rg]); pa.w = f32_to_bf16(acc[3][rg]);
                pb.x = f32_to_bf16(acc[4][rg]); pb.y = f32_to_bf16(acc[5][rg]);
                pb.z = f32_to_bf16(acc[6][rg]); pb.w = f32_to_bf16(acc[7][rg]);
                uint4 pk = { ((uint32_t)pa.y << 16) | pa.x, ((uint32_t)pa.w << 16) | pa.z,
                             ((uint32_t)pb.y << 16) | pb.x, ((uint32_t)pb.w << 16) | pb.z };
                *(uint4*)(T + (size_t)(n - n0) * TC + cb + 8 * r) = pk;
            }
        }
    } else {
        if (wave != 0) return;               // bias tail: 64 cols only
        int cb = 8192;
        bf16x8 bfr[4][2];
#pragma unroll
        for (int nt = 0; nt < 4; ++nt) {
            size_t cofs = (size_t)(cb + nt * 16 + r) * 64;
            bfr[nt][0] = *(const bf16x8*)(BmatT + cofs + q * 8);
            bfr[nt][1] = *(const bf16x8*)(BmatT + cofs + 32 + q * 8);
        }
#pragma unroll
        for (int mt = 0; mt < 8; ++mt) {
            int e = eb + mt * 16 + r;
            if (e >= n1) e = n1 - 1;
            bf16x8 afr0 = *(const bf16x8*)(outbf + (size_t)e * 64 + q * 8);
            bf16x8 afr1 = *(const bf16x8*)(outbf + (size_t)e * 64 + 32 + q * 8);
            f32x4 acc[4];
#pragma unroll
            for (int nt = 0; nt < 4; ++nt) {
                acc[nt] = __builtin_amdgcn_mfma_f32_16x16x32_bf16(afr0, bfr[nt][0], (f32x4){}, 0, 0, 0);
                acc[nt] = __builtin_amdgcn_mfma_f32_16x16x32_bf16(afr1, bfr[nt][1], acc[nt], 0, 0, 0);
            }
#pragma unroll
            for (int rg = 0; rg < 4; ++rg) {
                int n = eb + mt * 16 + q * 4 + rg;
                if (n >= n1) continue;
                ushort4 pk;
                pk.x = f32_to_bf16(acc[0][rg]);
                pk.y = f32_to_bf16(acc[1][rg]);
                pk.z = f32_to_bf16(acc[2][rg]);
                pk.w = f32_to_bf16(acc[3][rg]);
                *(ushort4*)(T + (size_t)(n - n0) * TC + cb + 4 * r) = pk;
            }
        }
    }
}

// per src-node wave, MFMA: msg[tile of 16 edges][64 o] = h[edges, 0:128] @ T''[n]
// msg stored BF16, col-permuted (mem col 4r+nt = mfma col nt*16+r, 8-B ushort4
// stores); rows indexed by EDGE ID (validated R12 layout). k_agg inverts the perm.
__global__ void k_msg(const unsigned short* __restrict__ h, const unsigned short* __restrict__ T,
                      const int* __restrict__ offS, const int* __restrict__ permS,
                      unsigned short* __restrict__ msg, int n0, int n1) {
    int wave = threadIdx.x >> 6, lane = threadIdx.x & 63;
    int n = n0 + blockIdx.x * 4 + wave;
    if (n >= n1) return;
    int beg = offS[n], end = offS[n + 1];
    if (beg == end) return;
    int r = lane & 15, q = lane >> 4;
    const unsigned short* Tb = T + (size_t)(n - n0) * TC;
    float bias[4];
#pragma unroll
    for (int nt = 0; nt < 4; ++nt)
        bias[nt] = bfu_to_f(Tb[8192 + nt * 16 + r]);
    for (int j0 = beg; j0 < end; j0 += 16) {
        int jc = j0 + r; if (jc >= end) jc = end - 1;
        int e = permS[jc];
        const unsigned short* he = h + (size_t)e * EHID;
        f32x4 acc[4] = {};
#pragma unroll
        for (int s = 0; s < 4; ++s) {        // K = 128 = 4*32
            bf16x8 afr = *(const bf16x8*)(he + s * 32 + q * 8);
#pragma unroll
            for (int nt = 0; nt < 4; ++nt) {
                bf16x8 bfr = *(const bf16x8*)(Tb + s * 2048 + (nt * 16 + r) * 32 + q * 8);
                acc[nt] = __builtin_amdgcn_mfma_f32_16x16x32_bf16(afr, bfr, acc[nt], 0, 0, 0);
            }
        }
#pragma unroll
        for (int rg = 0; rg < 4; ++rg) {
            int jr = j0 + q * 4 + rg;
            if (jr >= end) continue;
            int er = permS[jr];
            ushort4 pk;
            pk.x = f32_to_bf16(acc[0][rg] + bias[0]);
            pk.y = f32_to_bf16(acc[1][rg] + bias[1]);
            pk.z = f32_to_bf16(acc[2][rg] + bias[2]);
            pk.w = f32_to_bf16(acc[3][rg] + bias[3]);
            *(ushort4*)(msg + (size_t)er * 64 + 4 * r) = pk;
        }
    }
}

// exclusive prefix sum (one block per array; blockIdx.x: 0=S, 1=D)
__global__ void k_scan(const int* __restrict__ cntS, const int* __restrict__ cntD,
                       int* __restrict__ offS, int* __restrict__ offD,
                       int* __restrict__ curS, int* __restrict__ curD, int n, int total) {
    const int* cnt = blockIdx.x ? cntD : cntS;
    int* off = blockIdx.x ? offD : offS;
    int* cur = blockIdx.x ? curD : curS;
    __shared__ int part[256];
    int tid = threadIdx.x;
    int chunk = (n + 255) / 256;
    int c0 = tid * chunk, c1 = c0 + chunk; if (c1 > n) c1 = n; if (c0 > n) c0 = n;
    int s = 0;
    for (int i = c0; i < c1; ++i) s += cnt[i];
    part[tid] = s;
    __syncthreads();
    for (int st = 1; st < 256; st <<= 1) {
        int v = (tid >= st) ? part[tid - st] : 0;
        __syncthreads();
        part[tid] += v;
        __syncthreads();
    }
    int run = tid ? part[tid - 1] : 0;
    for (int i = c0; i < c1; ++i) { off[i] = run; cur[i] = run; run += cnt[i]; }
    if (tid == 0) off[n] = total;
}

__global__ void k_perm(const int* __restrict__ src, const int* __restrict__ dst,
                       int* __restrict__ curS, int* __restrict__ curD,
                       int* __restrict__ permS, int* __restrict__ permD, int n_edges) {
    int e = blockIdx.x * 256 + threadIdx.x;
    if (e >= n_edges) return;
    permS[atomicAdd(&curS[src[e]], 1)] = e;
    permD[atomicAdd(&curD[dst[e]], 1)] = e;
}

// per dst-node wave: out[d] = relu(sum msg + cbias); atomic-free gather of BF16
// rows (128 B each), software-pipelined 16 deep. msg cols stored permuted:
// lane's stored col l is semantic o=(l&3)*16+(l>>2).
// If stat != null (last step): block-reduce BN sums into stat (semantic index).
__global__ void k_agg(const unsigned short* __restrict__ msg, const int* __restrict__ offD,
                      const int* __restrict__ permD, const float* __restrict__ cbias,
                      float* __restrict__ outb, unsigned short* __restrict__ outbf,
                      float* __restrict__ stat, int n_nodes) {
    __shared__ float s1[256], s2[256];
    int wave = threadIdx.x >> 6, lane = threadIdx.x & 63;
    int d = blockIdx.x * 4 + wave;
    int o = (lane & 3) * 16 + (lane >> 2);
    float v = 0.f;
    if (d < n_nodes) {
        int beg = offD[d], end = offD[d + 1];
        float acc = 0.f;
        for (int j0 = beg; j0 < end; j0 += 16) {
            int nrem = end - j0;               // >= 1
            int idx[16];
#pragma unroll
            for (int k = 0; k < 16; ++k) {
                int jj = j0 + k; if (jj >= end) jj = j0;
                idx[k] = permD[jj];            // lane-uniform -> scalarized
            }
            unsigned short vals[16];
#pragma unroll
            for (int k = 0; k < 16; ++k)
                vals[k] = msg[(size_t)idx[k] * 64 + lane];   // 16 independent 128-B rows
#pragma unroll
            for (int k = 0; k < 16; ++k)
                if (k < nrem) acc += bfu_to_f(vals[k]);
        }
        v = fmaxf(acc + cbias[o], 0.f);
        outb[(size_t)d * 64 + o] = v;
        outbf[(size_t)d * 64 + o] = f32_to_bf16(v);
    }
    if (stat) {
        int tid = threadIdx.x;
        s1[tid] = v; s2[tid] = v * v;
        __syncthreads();
        if (tid < 64) {
            float A = s1[tid] + s1[64 + tid] + s1[128 + tid] + s1[192 + tid];
            float B = s2[tid] + s2[64 + tid] + s2[128 + tid] + s2[192 + tid];
            int os = (tid & 3) * 16 + (tid >> 2);   // semantic feature of stored col tid
            atomicAdd(&stat[os], A);
            atomicAdd(&stat[64 + os], B);
        }
    }
}

// bn_final fused in: every thread derives scale/shift from stat (identical arith)
__global__ void k_bn_apply(const float* __restrict__ out, const float* __restrict__ stat,
                           const float* __restrict__ gamma, const float* __restrict__ beta,
                           float* __restrict__ y, int n, int n_nodes) {
    int t = blockIdx.x * 256 + threadIdx.x;
    if (t >= n) return;
    int f = t & 63;
    float mean = stat[f] / n_nodes;
    float var  = stat[64 + f] / n_nodes - mean * mean;   // population var
    float inv  = rsqrtf(var + 1e-5f);
    float scale = gamma[f] * inv;
    float shift = beta[f] - mean * scale;
    y[t] = out[t] * scale + shift;
}

extern "C" void kernel_launch(void* const* d_in, const int* in_sizes, int n_in,
                              void* d_out, int out_size, void* d_ws, size_t ws_size,
                              hipStream_t stream) {
    const float* nf    = (const float*)d_in[0];
    const float* ef    = (const float*)d_in[1];
    const int*   src   = (const int*)d_in[2];
    const int*   dst   = (const int*)d_in[3];
    const float* W0    = (const float*)d_in[4];
    const float* b0    = (const float*)d_in[5];
    const float* We1   = (const float*)d_in[6];
    const float* be1   = (const float*)d_in[7];
    const float* We2   = (const float*)d_in[8];
    const float* be2   = (const float*)d_in[9];
    const float* cbias = (const float*)d_in[10];
    const float* gamma = (const float*)d_in[11];
    const float* beta  = (const float*)d_in[12];
    (void)n_in; (void)out_size;

    int n_nodes = in_sizes[0] / DIN;   // 10000
    int n_edges = in_sizes[2];         // 100000

    char* ws = (char*)d_ws;
    size_t off = 0;
    auto carve = [&](size_t bytes) -> void* {
        void* p = ws + off;
        off = (off + bytes + 255) & ~(size_t)255;
        return p;
    };
    unsigned short* h     = (unsigned short*)carve((size_t)n_edges * EHID * 2);  // 25.6 MB
    unsigned short* msg   = (unsigned short*)carve((size_t)n_edges * 64 * 2);    // 12.8 MB (bf16)
    float*          outb  = (float*)carve((size_t)n_nodes * HDIM * 4);
    unsigned short* outbf = (unsigned short*)carve((size_t)n_nodes * HDIM * 2);
    unsigned short* BmatT = (unsigned short*)carve((size_t)TC * 64 * 2);
    int*            offS  = (int*)carve((size_t)(n_nodes + 1) * 4);
    int*            offD  = (int*)carve((size_t)(n_nodes + 1) * 4);
    int*            curS  = (int*)carve((size_t)n_nodes * 4);
    int*            curD  = (int*)carve((size_t)n_nodes * 4);
    int*            permS = (int*)carve((size_t)n_edges * 4);
    int*            permD = (int*)carve((size_t)n_edges * 4);
    float*          stat  = (float*)carve(128 * 4 + (size_t)2 * n_nodes * 4); // stat + cntS + cntD
    int*            cntS  = (int*)(stat + 128);
    int*            cntD  = cntS + n_nodes;
    unsigned short* T     = (unsigned short*)(ws + off);
    size_t avail = ws_size > off ? ws_size - off : 0;
    long tcap = (long)(avail / ((size_t)TC * 2));   // ws-capacity bound (node rows)
    if (tcap > n_nodes) tcap = n_nodes;
    if (tcap < 64) tcap = 64;
    long tchunk = tcap;   // single chunk with current ws

    hipMemsetAsync(stat, 0, 128 * 4 + (size_t)2 * n_nodes * 4, stream);

    int nbN = (n_nodes + 3) / 4;            // 2500
    int nbE = (n_edges + 63) / 64;          // 1563 (MFMA edge path: 64 edges/block)
    int nbB = (TC * 64 + 255) / 256;        // 2064
    int nbH = (n_edges + 255) / 256;        // 391
    k_pro<<<dim3(nbN + nbE + nbB + nbH), 256, 0, stream>>>(
        nf, W0, b0, outb, outbf, ef, We1, be1, h, We2, be2, BmatT,
        src, dst, cntS, cntD, n_nodes, n_edges, nbN, nbE, nbB);
    k_scan<<<dim3(2), 256, 0, stream>>>(cntS, cntD, offS, offD, curS, curD, n_nodes, n_edges);
    k_perm<<<dim3((n_edges + 255) / 256), 256, 0, stream>>>(src, dst, curS, curD, permS, permD, n_edges);

    for (int step = 0; step < STEPS; ++step) {
        for (long n0 = 0; n0 < n_nodes; n0 += tchunk) {
            long n1 = n0 + tchunk; if (n1 > n_nodes) n1 = n_nodes;
            long cnt = n1 - n0;
            k_T<<<dim3(17, (cnt + 127) / 128), 256, 0, stream>>>(
                outbf, BmatT, T, (int)n0, (int)n1);
            k_msg<<<dim3((cnt + 3) / 4), 256, 0, stream>>>(
                h, T, offS, permS, msg, (int)n0, (int)n1);
        }
        k_agg<<<dim3((n_nodes + 3) / 4), 256, 0, stream>>>(
            msg, offD, permD, cbias, outb, outbf,
            (step == STEPS - 1) ? stat : (float*)nullptr, n_nodes);
    }

    k_bn_apply<<<dim3((n_nodes * HDIM + 255) / 256), 256, 0, stream>>>(
        outb, stat, gamma, beta, (float*)d_out, n_nodes * HDIM, n_nodes);
}